// Round 10
// baseline (180.928 us; speedup 1.0000x reference)
//
#include <hip/hip_runtime.h>
#include <hip/hip_bf16.h>
#include <math.h>

// Contrastive (NT-Xent-like) loss over x[16384][64] fp32.
//   x_hat = sqrt(2*log2e) * x / ||x||   (so x_hat_i.x_hat_j = sim/T * log2e,
//                                        and exp(sim/T) = exp2(x_hat_i.x_hat_j))
//   den[j] = sum_i exp2(x_hat_i . x_hat_j) - e^2
//   num[j] = exp2(x_hat_{j^1} . x_hat_j)
//   out = -log( mean_j num[j] / den[j] )
//
// Round 10: r9's profile unmasked the "fixed overhead": the harness's 0xAA
// poison fill of the 256 MB workspace (43 us at 78% HBM peak) — untouchable.
// den (~40 us) shows ~2x stall over counted issue -> occupancy/latency levers:
//   (1) A-fragments read DIRECTLY from global/L2 (contiguous short8 per lane;
//       per instruction the (p,m) lanes tile 16 rows x one 64-B line, 4
//       lanes/line, zero overfetch) — As LDS buffer deleted, LDS 32->16 KB,
//       occupancy 5->6 blocks/CU (launch_bounds(256,6); VGPR was 80 < 85 cap).
//   (2) Flat per-wave S stores: S b-axis widened to 256 slots
//       (colsums -> (a=tj, b=2ti+wi); rowsums -> (a=ti, b=2tj+wj); diag
//       writes colsums only, exactly filling b=2a slots; every slot written
//       once). Each lane stores its own butterfly result (coalesced 256
//       B/wave) — LDS cross-wave combine + 2 barriers deleted; den keeps ONE
//       __syncthreads. S 8->16 MB (+~2.6 us HBM, cheap vs the cycles saved).
// Kept verified: B-side XOR-swizzled conflict-free LDS via global_load_lds
// width=16, 2x2 wave MFMA 16x16x32_bf16, exp2 prescale, value-halving
// butterflies, kernel boundary as the only cross-XCD flush (r5/r7 lessons),
// bf16 prebake normalize (r8 lesson: don't re-normalize per block).

#define NROWS 16384
#define KDIM 64
#define NTILE 128
#define NTB (NROWS / NTILE)          // 128 tile-blocks per side
#define NPAIRS (NTB * (NTB + 1) / 2) // 8256 upper-triangle tile pairs
#define BSLOTS (2 * NTB)             // 256 b-slots per S row

typedef __attribute__((ext_vector_type(8))) short short8;   // 8 bf16 = 4 VGPRs
typedef __attribute__((ext_vector_type(4))) float f32x4;
typedef __attribute__((ext_vector_type(2))) float f32x2;

__device__ __forceinline__ float exp2_fast(float x) {
#if __has_builtin(__builtin_amdgcn_exp2f)
    return __builtin_amdgcn_exp2f(x);   // bare v_exp_f32
#else
    return exp2f(x);
#endif
}

// async global->LDS DMA, 16 B per lane; LDS side must be uniform + lane*16.
__device__ __forceinline__ void load_lds16(const void* g, void* l) {
    __builtin_amdgcn_global_load_lds((const __attribute__((address_space(1))) unsigned int*)g,
                                     (__attribute__((address_space(3))) unsigned int*)l,
                                     16, 0, 0);
}

// ---- kernel A: row-normalize, prescale by sqrt(2*log2e) -> bf16 -----------
// 64 rows/block, 4 lanes/row, 16 floats/thread. Also zeroes ctrl/accum.
__global__ __launch_bounds__(256) void normalize_kernel(const float* __restrict__ x,
                                                        unsigned short* __restrict__ xnb,
                                                        unsigned int* __restrict__ ctrl,
                                                        float* __restrict__ accum) {
    const int t = threadIdx.x;
    const int r = blockIdx.x * 64 + (t >> 2);
    const int q = t & 3;
    const float4* xr = (const float4*)(x + (size_t)r * KDIM) + q * 4;
    const float4 v0 = xr[0], v1 = xr[1], v2 = xr[2], v3 = xr[3];
    float ss = v0.x * v0.x + v0.y * v0.y + v0.z * v0.z + v0.w * v0.w
             + v1.x * v1.x + v1.y * v1.y + v1.z * v1.z + v1.w * v1.w
             + v2.x * v2.x + v2.y * v2.y + v2.z * v2.z + v2.w * v2.w
             + v3.x * v3.x + v3.y * v3.y + v3.z * v3.z + v3.w * v3.w;
    ss += __shfl_xor(ss, 1, 64);
    ss += __shfl_xor(ss, 2, 64);
    // sqrt(2*log2(e)) = sqrt(2.88539008) = 1.69864404
    const float a = 1.69864404f * rsqrtf(fmaxf(ss, 1e-16f));
    const float vals[16] = {v0.x * a, v0.y * a, v0.z * a, v0.w * a,
                            v1.x * a, v1.y * a, v1.z * a, v1.w * a,
                            v2.x * a, v2.y * a, v2.z * a, v2.w * a,
                            v3.x * a, v3.y * a, v3.z * a, v3.w * a};
    union { unsigned short us[16]; uint4 v[2]; } o;
    #pragma unroll
    for (int k = 0; k < 16; k++) {
        __hip_bfloat16 b = __float2bfloat16(vals[k]);
        o.us[k] = *(unsigned short*)&b;
    }
    uint4* dst = (uint4*)(xnb + (size_t)r * KDIM);
    dst[q * 2] = o.v[0];
    dst[q * 2 + 1] = o.v[1];
    if (blockIdx.x == 0 && t == 0) { ctrl[0] = 0u; ctrl[1] = 0u; accum[0] = 0.0f; }
}

// ---- kernel B: symmetric tile-pair partial sums ---------------------------
// Block = upper-triangle tile pair (ti<=tj). 4 waves 2x2, 64x64/wave,
// mfma_f32_16x16x32_bf16 (A-frag: lane m=l&15 holds k=(l>>4)*8+e;
// C/D: col=l&15, row=(l>>4)*4+reg). B staged in LDS (XOR-swizzled chunk(r,q)
// at r*8 + (q^(r&7)), global_load_lds width=16); A-fragments loaded straight
// from global (contiguous short8, 4 lanes per 64-B line). 16 KB LDS.
__global__ __launch_bounds__(256, 6) void den_kernel(const unsigned short* __restrict__ xnb,
                                                     float* __restrict__ S,
                                                     float* __restrict__ num) {
    __shared__ float4 Bs[1024];  // 16 KB

    // triangular decode (f32; loops absorb rounding): blockIdx.x -> (ti, tj)
    const int bt = blockIdx.x;
    int ti = (int)((257.0f - sqrtf(66049.0f - 8.0f * (float)bt)) * 0.5f);
    while (ti * NTB - ti * (ti - 1) / 2 > bt) ti--;
    while ((ti + 1) * NTB - (ti + 1) * ti / 2 <= bt) ti++;
    const int tj = ti + (bt - (ti * NTB - ti * (ti - 1) / 2));
    const int ib = ti * NTILE, jb = tj * NTILE;
    const bool diag = (ti == tj);

    const int t = threadIdx.x;
    // stage B: chunk c -> row r=c>>3, k-chunk q=(c&7)^(r&7). Global side is a
    // per-lane VGPR address (swizzle allowed); LDS side is uniform + lane*16.
    #pragma unroll
    for (int s = 0; s < 4; s++) {
        const int c = s * 256 + t;
        const int r = c >> 3;
        const int q = (c & 7) ^ (r & 7);
        load_lds16(xnb + (size_t)(jb + r) * KDIM + q * 8, &Bs[c]);
    }

    const int lane = t & 63, w = t >> 6;
    const int wi = w >> 1, wj = w & 1;
    const int m = lane & 15, p = lane >> 4;

    const f32x4 zero = {0.f, 0.f, 0.f, 0.f};
    f32x4 acc[4][4];
    #pragma unroll
    for (int it = 0; it < 4; it++)
        #pragma unroll
        for (int jt = 0; jt < 4; jt++) acc[it][jt] = zero;

    __syncthreads();   // compiler drains vmcnt before s_barrier (covers DMA)

    #pragma unroll
    for (int kc = 0; kc < 2; kc++) {
        short8 af[4], bf[4];
        // A-fragment direct from global: contiguous 16 B at row (ib+wi*64+
        // it*16+m), k-offset kc*32+p*8. Lanes p=0..3 of a row tile one 64-B
        // line; 16 rows/instruction -> 16 lines, zero overfetch (L2-resident).
        #pragma unroll
        for (int it = 0; it < 4; it++)
            af[it] = *(const short8*)(xnb + (size_t)(ib + wi * 64 + it * 16 + m) * KDIM + kc * 32 + p * 8);
        const int qx = ((kc << 2) | p) ^ (m & 7);
        #pragma unroll
        for (int jt = 0; jt < 4; jt++)
            bf[jt] = *(const short8*)((const unsigned short*)Bs + ((wj * 64 + jt * 16 + m) * 8 + qx) * 8);
        #pragma unroll
        for (int it = 0; it < 4; it++)
            #pragma unroll
            for (int jt = 0; jt < 4; jt++)
                acc[it][jt] = __builtin_amdgcn_mfma_f32_16x16x32_bf16(af[it], bf[jt], acc[it][jt], 0, 0, 0);
    }

    // epilogue: exp2; packed (v_pk_add_f32) accumulation of col/row partials
    f32x2 cs01 = {0.f, 0.f}, cs23 = {0.f, 0.f};
    float rs[16];
    #pragma unroll
    for (int it = 0; it < 4; it++) {
        #pragma unroll
        for (int reg = 0; reg < 4; reg++) {
            f32x2 e01, e23;
            e01.x = exp2_fast(acc[it][0][reg]);
            e01.y = exp2_fast(acc[it][1][reg]);
            e23.x = exp2_fast(acc[it][2][reg]);
            e23.y = exp2_fast(acc[it][3][reg]);
            cs01 += e01;
            cs23 += e23;
            const f32x2 rp = e01 + e23;
            rs[it * 4 + reg] = rp.x + rp.y;
        }
    }
    float cs[4] = {cs01.x, cs01.y, cs23.x, cs23.y};

    // colsum butterfly over p (value-halving): lane ends with column p*16+m
    {
        const bool hb = (p & 2) != 0;
        float s0 = hb ? cs[0] : cs[2], k0 = hb ? cs[2] : cs[0];
        float s1 = hb ? cs[1] : cs[3], k1 = hb ? cs[3] : cs[1];
        cs[0] = k0 + __shfl_xor(s0, 32, 64);
        cs[1] = k1 + __shfl_xor(s1, 32, 64);
        const bool lb = (p & 1) != 0;
        float s2 = lb ? cs[0] : cs[1], k2 = lb ? cs[1] : cs[0];
        cs[0] = k2 + __shfl_xor(s2, 16, 64);
    }
    // flat store: colsum partial (over wi-half rows) for column wj*64+p*16+m
    //   -> S[a=tj][b=2*ti+wi][c]   (contribution to den[jb + c])
    S[((size_t)tj * BSLOTS + 2 * ti + wi) * NTILE + wj * 64 + p * 16 + m] = cs[0];

    if (!diag) {
        // rowsum butterfly over m (value-halving, 15 shfl): lane ends with
        // row (m>>2)*16 + p*4 + (m&3) of its wi-half
        #pragma unroll
        for (int k = 0; k < 8; k++) {
            const float snd = (m & 8) ? rs[k] : rs[k + 8];
            const float kp  = (m & 8) ? rs[k + 8] : rs[k];
            rs[k] = kp + __shfl_xor(snd, 8, 64);
        }
        #pragma unroll
        for (int k = 0; k < 4; k++) {
            const float snd = (m & 4) ? rs[k] : rs[k + 4];
            const float kp  = (m & 4) ? rs[k + 4] : rs[k];
            rs[k] = kp + __shfl_xor(snd, 4, 64);
        }
        #pragma unroll
        for (int k = 0; k < 2; k++) {
            const float snd = (m & 2) ? rs[k] : rs[k + 2];
            const float kp  = (m & 2) ? rs[k + 2] : rs[k];
            rs[k] = kp + __shfl_xor(snd, 2, 64);
        }
        {
            const float snd = (m & 1) ? rs[0] : rs[1];
            const float kp  = (m & 1) ? rs[1] : rs[0];
            rs[0] = kp + __shfl_xor(snd, 1, 64);
        }
        // flat store: rowsum partial (over wj-half cols) for row
        // wi*64 + (m>>2)*16 + p*4 + (m&3)
        //   -> S[a=ti][b=2*tj+wj][r]   (contribution to den[ib + r]).
        // Diag blocks skip this; their b=2a slots are filled by colsums.
        S[((size_t)ti * BSLOTS + 2 * tj + wj) * NTILE + wi * 64 + ((m >> 2) * 16 + p * 4 + (m & 3))] = rs[0];
    } else if (wi == wj) {
        // num[j] = exp2(acc(row j^1, col j)) from the diagonal tile: element
        // (m^1, m) of sub-tile it lives in lane ((m^1)>>2, m), reg (m^1)&3.
        const int pc = m ^ 1;
        if ((pc >> 2) == p) {
            #pragma unroll
            for (int it = 0; it < 4; it++)
                num[jb + wj * 64 + it * 16 + m] = exp2_fast(acc[it][it][pc & 3]);
        }
    }
}

// ---- kernel C: den[a*128+c] = sum_b S[a][b][c]; ratio + global sum + log ---
// 128 blocks; ticket write of the final scalar (r6-verified).
__global__ __launch_bounds__(256) void reduce_kernel(const float* __restrict__ S,
                                                     const float* __restrict__ num,
                                                     unsigned int* __restrict__ ctrl,
                                                     float* __restrict__ accum,
                                                     float* __restrict__ out) {
    const int a = blockIdx.x;
    const int t = threadIdx.x;
    const int c = t & 127, h = t >> 7;     // h splits the 256 b-slots in two
    const float* base = S + (size_t)a * (BSLOTS * NTILE) + (size_t)h * 128 * NTILE + c;
    float s = 0.0f;
    #pragma unroll 8
    for (int b = 0; b < 128; b++) s += base[(size_t)b * NTILE];

    __shared__ float part[NTILE];
    __shared__ float wsum[4];
    if (h == 0) part[c] = s;
    __syncthreads();

    float r = 0.0f;
    if (h == 1) {
        const float E2 = 7.38905609893065f;  // exp(1/T)=exp(2): diagonal removal
        r = num[a * NTILE + c] / ((part[c] + s) - E2);
    }
    #pragma unroll
    for (int o = 32; o > 0; o >>= 1) r += __shfl_xor(r, o, 64);
    if ((t & 63) == 0) wsum[t >> 6] = r;
    __syncthreads();
    if (t == 0) {
        const float bsum = (wsum[0] + wsum[1]) + (wsum[2] + wsum[3]);
        __hip_atomic_fetch_add(accum, bsum, __ATOMIC_RELAXED, __HIP_MEMORY_SCOPE_AGENT);
        const unsigned int tk = __hip_atomic_fetch_add(&ctrl[1], 1u, __ATOMIC_ACQ_REL, __HIP_MEMORY_SCOPE_AGENT);
        if (tk == (unsigned)(NTB - 1)) {   // last block writes the loss
            const float total = __hip_atomic_load(accum, __ATOMIC_ACQUIRE, __HIP_MEMORY_SCOPE_AGENT);
            out[0] = -logf(total / (float)NROWS);
        }
    }
}

extern "C" void kernel_launch(void* const* d_in, const int* in_sizes, int n_in,
                              void* d_out, int out_size, void* d_ws, size_t ws_size,
                              hipStream_t stream) {
    const float* x = (const float*)d_in[0];
    float* out = (float*)d_out;

    // ws: xnb [2 MB bf16] | num [64 KB f32] | accum [1 f32] | ctrl [2 u32]
    //   | S [128 x 256 x 128 f32 = 16 MB]
    unsigned short* xnb = (unsigned short*)d_ws;
    float* num = (float*)((char*)d_ws + (size_t)NROWS * KDIM * sizeof(unsigned short));
    float* accum = num + NROWS;
    unsigned int* ctrl = (unsigned int*)(accum + 1);
    float* S = (float*)(ctrl + 2);

    normalize_kernel<<<NROWS / 64, 256, 0, stream>>>(x, xnb, ctrl, accum);
    den_kernel<<<NPAIRS, 256, 0, stream>>>(xnb, S, num);
    reduce_kernel<<<NTB, 256, 0, stream>>>(S, num, ctrl, accum, out);
}

// Round 11
// 118.890 us; speedup vs baseline: 1.5218x; 1.5218x over previous
//
#include <hip/hip_runtime.h>
#include <hip/hip_bf16.h>
#include <math.h>

// Contrastive (NT-Xent-like) loss over x[16384][64] fp32.
//   x_hat = sqrt(2*log2e) * x / ||x||   (so x_hat_i.x_hat_j = sim/T * log2e,
//                                        and exp(sim/T) = exp2(x_hat_i.x_hat_j))
//   den[j] = sum_i exp2(x_hat_i . x_hat_j) - e^2
//   num[j] = exp2(x_hat_{j^1} . x_hat_j)
//   out = -log( mean_j num[j] / den[j] )
//
// Round 11: r10's __launch_bounds__(256,6) capped the unified VGPR/AGPR
// budget at ~85 regs/thread; the kernel needs ~80 VGPR + 64-reg MFMA
// accumulator tile -> the compiler SPILLED THE ACCUMULATORS to scratch
// (VGPR_Count 80->40, WRITE_SIZE 16.5->345 MB, den 40->120 us memory-bound).
// Fix: plain __launch_bounds__(256); natural allocation (r6/r9-verified
// no-spill) + 16 KB LDS gives 6 blocks/CU anyway. Everything else = r10:
//   - A-fragments direct from global/L2 (contiguous short8/lane; (p,m) lanes
//     tile 16 rows x one 64-B line each; As LDS buffer deleted);
//   - flat per-wave S stores (b-axis 256 slots: colsums -> (a=tj, b=2ti+wi),
//     rowsums -> (a=ti, b=2tj+wj); diag fills b=2a with colsums; each lane
//     stores its own butterfly output, coalesced 256 B/wave; ONE barrier);
//   - B-side XOR-swizzled LDS via global_load_lds width=16 (0 conflicts);
//   - exp2 prescale, value-halving butterflies, bf16 prebake normalize,
//     kernel boundary as the only cross-XCD flush (r5/r7 lessons).

#define NROWS 16384
#define KDIM 64
#define NTILE 128
#define NTB (NROWS / NTILE)          // 128 tile-blocks per side
#define NPAIRS (NTB * (NTB + 1) / 2) // 8256 upper-triangle tile pairs
#define BSLOTS (2 * NTB)             // 256 b-slots per S row

typedef __attribute__((ext_vector_type(8))) short short8;   // 8 bf16 = 4 VGPRs
typedef __attribute__((ext_vector_type(4))) float f32x4;
typedef __attribute__((ext_vector_type(2))) float f32x2;

__device__ __forceinline__ float exp2_fast(float x) {
#if __has_builtin(__builtin_amdgcn_exp2f)
    return __builtin_amdgcn_exp2f(x);   // bare v_exp_f32
#else
    return exp2f(x);
#endif
}

// async global->LDS DMA, 16 B per lane; LDS side must be uniform + lane*16.
__device__ __forceinline__ void load_lds16(const void* g, void* l) {
    __builtin_amdgcn_global_load_lds((const __attribute__((address_space(1))) unsigned int*)g,
                                     (__attribute__((address_space(3))) unsigned int*)l,
                                     16, 0, 0);
}

// ---- kernel A: row-normalize, prescale by sqrt(2*log2e) -> bf16 -----------
// 64 rows/block, 4 lanes/row, 16 floats/thread. Also zeroes ctrl/accum.
__global__ __launch_bounds__(256) void normalize_kernel(const float* __restrict__ x,
                                                        unsigned short* __restrict__ xnb,
                                                        unsigned int* __restrict__ ctrl,
                                                        float* __restrict__ accum) {
    const int t = threadIdx.x;
    const int r = blockIdx.x * 64 + (t >> 2);
    const int q = t & 3;
    const float4* xr = (const float4*)(x + (size_t)r * KDIM) + q * 4;
    const float4 v0 = xr[0], v1 = xr[1], v2 = xr[2], v3 = xr[3];
    float ss = v0.x * v0.x + v0.y * v0.y + v0.z * v0.z + v0.w * v0.w
             + v1.x * v1.x + v1.y * v1.y + v1.z * v1.z + v1.w * v1.w
             + v2.x * v2.x + v2.y * v2.y + v2.z * v2.z + v2.w * v2.w
             + v3.x * v3.x + v3.y * v3.y + v3.z * v3.z + v3.w * v3.w;
    ss += __shfl_xor(ss, 1, 64);
    ss += __shfl_xor(ss, 2, 64);
    // sqrt(2*log2(e)) = sqrt(2.88539008) = 1.69864404
    const float a = 1.69864404f * rsqrtf(fmaxf(ss, 1e-16f));
    const float vals[16] = {v0.x * a, v0.y * a, v0.z * a, v0.w * a,
                            v1.x * a, v1.y * a, v1.z * a, v1.w * a,
                            v2.x * a, v2.y * a, v2.z * a, v2.w * a,
                            v3.x * a, v3.y * a, v3.z * a, v3.w * a};
    union { unsigned short us[16]; uint4 v[2]; } o;
    #pragma unroll
    for (int k = 0; k < 16; k++) {
        __hip_bfloat16 b = __float2bfloat16(vals[k]);
        o.us[k] = *(unsigned short*)&b;
    }
    uint4* dst = (uint4*)(xnb + (size_t)r * KDIM);
    dst[q * 2] = o.v[0];
    dst[q * 2 + 1] = o.v[1];
    if (blockIdx.x == 0 && t == 0) { ctrl[0] = 0u; ctrl[1] = 0u; accum[0] = 0.0f; }
}

// ---- kernel B: symmetric tile-pair partial sums ---------------------------
// Block = upper-triangle tile pair (ti<=tj). 4 waves 2x2, 64x64/wave,
// mfma_f32_16x16x32_bf16 (A-frag: lane m=l&15 holds k=(l>>4)*8+e;
// C/D: col=l&15, row=(l>>4)*4+reg). B staged in LDS (XOR-swizzled chunk(r,q)
// at r*8 + (q^(r&7)), global_load_lds width=16); A-fragments loaded straight
// from global (contiguous short8, 4 lanes per 64-B line). 16 KB LDS.
__global__ __launch_bounds__(256) void den_kernel(const unsigned short* __restrict__ xnb,
                                                  float* __restrict__ S,
                                                  float* __restrict__ num) {
    __shared__ float4 Bs[1024];  // 16 KB

    // triangular decode (f32; loops absorb rounding): blockIdx.x -> (ti, tj)
    const int bt = blockIdx.x;
    int ti = (int)((257.0f - sqrtf(66049.0f - 8.0f * (float)bt)) * 0.5f);
    while (ti * NTB - ti * (ti - 1) / 2 > bt) ti--;
    while ((ti + 1) * NTB - (ti + 1) * ti / 2 <= bt) ti++;
    const int tj = ti + (bt - (ti * NTB - ti * (ti - 1) / 2));
    const int ib = ti * NTILE, jb = tj * NTILE;
    const bool diag = (ti == tj);

    const int t = threadIdx.x;
    // stage B: chunk c -> row r=c>>3, k-chunk q=(c&7)^(r&7). Global side is a
    // per-lane VGPR address (swizzle allowed); LDS side is uniform + lane*16.
    #pragma unroll
    for (int s = 0; s < 4; s++) {
        const int c = s * 256 + t;
        const int r = c >> 3;
        const int q = (c & 7) ^ (r & 7);
        load_lds16(xnb + (size_t)(jb + r) * KDIM + q * 8, &Bs[c]);
    }

    const int lane = t & 63, w = t >> 6;
    const int wi = w >> 1, wj = w & 1;
    const int m = lane & 15, p = lane >> 4;

    const f32x4 zero = {0.f, 0.f, 0.f, 0.f};
    f32x4 acc[4][4];
    #pragma unroll
    for (int it = 0; it < 4; it++)
        #pragma unroll
        for (int jt = 0; jt < 4; jt++) acc[it][jt] = zero;

    __syncthreads();   // compiler drains vmcnt before s_barrier (covers DMA)

    #pragma unroll
    for (int kc = 0; kc < 2; kc++) {
        short8 af[4], bf[4];
        // A-fragment direct from global: contiguous 16 B at row (ib+wi*64+
        // it*16+m), k-offset kc*32+p*8. Lanes p=0..3 of a row tile one 64-B
        // line; 16 rows/instruction -> 16 lines, zero overfetch (L2-resident).
        #pragma unroll
        for (int it = 0; it < 4; it++)
            af[it] = *(const short8*)(xnb + (size_t)(ib + wi * 64 + it * 16 + m) * KDIM + kc * 32 + p * 8);
        const int qx = ((kc << 2) | p) ^ (m & 7);
        #pragma unroll
        for (int jt = 0; jt < 4; jt++)
            bf[jt] = *(const short8*)((const unsigned short*)Bs + ((wj * 64 + jt * 16 + m) * 8 + qx) * 8);
        #pragma unroll
        for (int it = 0; it < 4; it++)
            #pragma unroll
            for (int jt = 0; jt < 4; jt++)
                acc[it][jt] = __builtin_amdgcn_mfma_f32_16x16x32_bf16(af[it], bf[jt], acc[it][jt], 0, 0, 0);
    }

    // epilogue: exp2; packed (v_pk_add_f32) accumulation of col/row partials
    f32x2 cs01 = {0.f, 0.f}, cs23 = {0.f, 0.f};
    float rs[16];
    #pragma unroll
    for (int it = 0; it < 4; it++) {
        #pragma unroll
        for (int reg = 0; reg < 4; reg++) {
            f32x2 e01, e23;
            e01.x = exp2_fast(acc[it][0][reg]);
            e01.y = exp2_fast(acc[it][1][reg]);
            e23.x = exp2_fast(acc[it][2][reg]);
            e23.y = exp2_fast(acc[it][3][reg]);
            cs01 += e01;
            cs23 += e23;
            const f32x2 rp = e01 + e23;
            rs[it * 4 + reg] = rp.x + rp.y;
        }
    }
    float cs[4] = {cs01.x, cs01.y, cs23.x, cs23.y};

    // colsum butterfly over p (value-halving): lane ends with column p*16+m
    {
        const bool hb = (p & 2) != 0;
        float s0 = hb ? cs[0] : cs[2], k0 = hb ? cs[2] : cs[0];
        float s1 = hb ? cs[1] : cs[3], k1 = hb ? cs[3] : cs[1];
        cs[0] = k0 + __shfl_xor(s0, 32, 64);
        cs[1] = k1 + __shfl_xor(s1, 32, 64);
        const bool lb = (p & 1) != 0;
        float s2 = lb ? cs[0] : cs[1], k2 = lb ? cs[1] : cs[0];
        cs[0] = k2 + __shfl_xor(s2, 16, 64);
    }
    // flat store: colsum partial (over wi-half rows) for column wj*64+p*16+m
    //   -> S[a=tj][b=2*ti+wi][c]   (contribution to den[jb + c])
    S[((size_t)tj * BSLOTS + 2 * ti + wi) * NTILE + wj * 64 + p * 16 + m] = cs[0];

    if (!diag) {
        // rowsum butterfly over m (value-halving, 15 shfl): lane ends with
        // row (m>>2)*16 + p*4 + (m&3) of its wi-half
        #pragma unroll
        for (int k = 0; k < 8; k++) {
            const float snd = (m & 8) ? rs[k] : rs[k + 8];
            const float kp  = (m & 8) ? rs[k + 8] : rs[k];
            rs[k] = kp + __shfl_xor(snd, 8, 64);
        }
        #pragma unroll
        for (int k = 0; k < 4; k++) {
            const float snd = (m & 4) ? rs[k] : rs[k + 4];
            const float kp  = (m & 4) ? rs[k + 4] : rs[k];
            rs[k] = kp + __shfl_xor(snd, 4, 64);
        }
        #pragma unroll
        for (int k = 0; k < 2; k++) {
            const float snd = (m & 2) ? rs[k] : rs[k + 2];
            const float kp  = (m & 2) ? rs[k + 2] : rs[k];
            rs[k] = kp + __shfl_xor(snd, 2, 64);
        }
        {
            const float snd = (m & 1) ? rs[0] : rs[1];
            const float kp  = (m & 1) ? rs[1] : rs[0];
            rs[0] = kp + __shfl_xor(snd, 1, 64);
        }
        // flat store: rowsum partial (over wj-half cols) for row
        // wi*64 + (m>>2)*16 + p*4 + (m&3)
        //   -> S[a=ti][b=2*tj+wj][r]   (contribution to den[ib + r]).
        // Diag blocks skip this; their b=2a slots are filled by colsums.
        S[((size_t)ti * BSLOTS + 2 * tj + wj) * NTILE + wi * 64 + ((m >> 2) * 16 + p * 4 + (m & 3))] = rs[0];
    } else if (wi == wj) {
        // num[j] = exp2(acc(row j^1, col j)) from the diagonal tile: element
        // (m^1, m) of sub-tile it lives in lane ((m^1)>>2, m), reg (m^1)&3.
        const int pc = m ^ 1;
        if ((pc >> 2) == p) {
            #pragma unroll
            for (int it = 0; it < 4; it++)
                num[jb + wj * 64 + it * 16 + m] = exp2_fast(acc[it][it][pc & 3]);
        }
    }
}

// ---- kernel C: den[a*128+c] = sum_b S[a][b][c]; ratio + global sum + log ---
// 128 blocks; ticket write of the final scalar (r6-verified).
__global__ __launch_bounds__(256) void reduce_kernel(const float* __restrict__ S,
                                                     const float* __restrict__ num,
                                                     unsigned int* __restrict__ ctrl,
                                                     float* __restrict__ accum,
                                                     float* __restrict__ out) {
    const int a = blockIdx.x;
    const int t = threadIdx.x;
    const int c = t & 127, h = t >> 7;     // h splits the 256 b-slots in two
    const float* base = S + (size_t)a * (BSLOTS * NTILE) + (size_t)h * 128 * NTILE + c;
    float s = 0.0f;
    #pragma unroll 8
    for (int b = 0; b < 128; b++) s += base[(size_t)b * NTILE];

    __shared__ float part[NTILE];
    __shared__ float wsum[4];
    if (h == 0) part[c] = s;
    __syncthreads();

    float r = 0.0f;
    if (h == 1) {
        const float E2 = 7.38905609893065f;  // exp(1/T)=exp(2): diagonal removal
        r = num[a * NTILE + c] / ((part[c] + s) - E2);
    }
    #pragma unroll
    for (int o = 32; o > 0; o >>= 1) r += __shfl_xor(r, o, 64);
    if ((t & 63) == 0) wsum[t >> 6] = r;
    __syncthreads();
    if (t == 0) {
        const float bsum = (wsum[0] + wsum[1]) + (wsum[2] + wsum[3]);
        __hip_atomic_fetch_add(accum, bsum, __ATOMIC_RELAXED, __HIP_MEMORY_SCOPE_AGENT);
        const unsigned int tk = __hip_atomic_fetch_add(&ctrl[1], 1u, __ATOMIC_ACQ_REL, __HIP_MEMORY_SCOPE_AGENT);
        if (tk == (unsigned)(NTB - 1)) {   // last block writes the loss
            const float total = __hip_atomic_load(accum, __ATOMIC_ACQUIRE, __HIP_MEMORY_SCOPE_AGENT);
            out[0] = -logf(total / (float)NROWS);
        }
    }
}

extern "C" void kernel_launch(void* const* d_in, const int* in_sizes, int n_in,
                              void* d_out, int out_size, void* d_ws, size_t ws_size,
                              hipStream_t stream) {
    const float* x = (const float*)d_in[0];
    float* out = (float*)d_out;

    // ws: xnb [2 MB bf16] | num [64 KB f32] | accum [1 f32] | ctrl [2 u32]
    //   | S [128 x 256 x 128 f32 = 16 MB]
    unsigned short* xnb = (unsigned short*)d_ws;
    float* num = (float*)((char*)d_ws + (size_t)NROWS * KDIM * sizeof(unsigned short));
    float* accum = num + NROWS;
    unsigned int* ctrl = (unsigned int*)(accum + 1);
    float* S = (float*)(ctrl + 2);

    normalize_kernel<<<NROWS / 64, 256, 0, stream>>>(x, xnb, ctrl, accum);
    den_kernel<<<NPAIRS, 256, 0, stream>>>(xnb, S, num);
    reduce_kernel<<<NTB, 256, 0, stream>>>(S, num, ctrl, accum, out);
}

// Round 12
// 106.536 us; speedup vs baseline: 1.6983x; 1.1160x over previous
//
#include <hip/hip_runtime.h>
#include <hip/hip_bf16.h>
#include <math.h>

// Contrastive (NT-Xent-like) loss over x[16384][64] fp32.
//   x_hat = sqrt(2*log2e) * x / ||x||   (so x_hat_i.x_hat_j = sim/T * log2e,
//                                        and exp(sim/T) = exp2(x_hat_i.x_hat_j))
//   den[j] = sum_i exp2(x_hat_i . x_hat_j) - e^2
//   num[j] = exp2(x_hat_{j^1} . x_hat_j)
//   out = -log( mean_j num[j] / den[j] )
//
// Round 12: r11 attribution — A-direct-from-global was the regression
// (~+16 us: 8 L2 round-trips in the MFMA dep chain after the barrier, and
// occupancy stayed register-bound at 3 blocks/CU [80 arch + 64 acc VGPR],
// so 16 KB LDS bought nothing). Reinstate r9's LDS-staged A (DMA prefetch
// before the barrier hides all 8 loads at once); KEEP r10's flat per-wave
// S stores — the change that only removes work (LDS cross-wave combine +
// 2 barriers deleted; den has ONE __syncthreads).
// Proven config: global_load_lds width=16 both tiles, XOR-swizzled
// conflict-free LDS, 2x2 wave MFMA 16x16x32_bf16, exp2 prescale, pk_add
// epilogue, value-halving butterflies, bf16 prebake normalize, kernel
// boundary as the only cross-XCD flush (r5/r7 lessons), no launch_bounds
// waves-clamp (r10 spill lesson).

#define NROWS 16384
#define KDIM 64
#define NTILE 128
#define NTB (NROWS / NTILE)          // 128 tile-blocks per side
#define NPAIRS (NTB * (NTB + 1) / 2) // 8256 upper-triangle tile pairs
#define BSLOTS (2 * NTB)             // 256 b-slots per S row

typedef __attribute__((ext_vector_type(8))) short short8;   // 8 bf16 = 4 VGPRs
typedef __attribute__((ext_vector_type(4))) float f32x4;
typedef __attribute__((ext_vector_type(2))) float f32x2;

__device__ __forceinline__ float exp2_fast(float x) {
#if __has_builtin(__builtin_amdgcn_exp2f)
    return __builtin_amdgcn_exp2f(x);   // bare v_exp_f32
#else
    return exp2f(x);
#endif
}

// async global->LDS DMA, 16 B per lane; LDS side must be uniform + lane*16.
__device__ __forceinline__ void load_lds16(const void* g, void* l) {
    __builtin_amdgcn_global_load_lds((const __attribute__((address_space(1))) unsigned int*)g,
                                     (__attribute__((address_space(3))) unsigned int*)l,
                                     16, 0, 0);
}

// ---- kernel A: row-normalize, prescale by sqrt(2*log2e) -> bf16 -----------
// 64 rows/block, 4 lanes/row, 16 floats/thread. Also zeroes ctrl/accum.
__global__ __launch_bounds__(256) void normalize_kernel(const float* __restrict__ x,
                                                        unsigned short* __restrict__ xnb,
                                                        unsigned int* __restrict__ ctrl,
                                                        float* __restrict__ accum) {
    const int t = threadIdx.x;
    const int r = blockIdx.x * 64 + (t >> 2);
    const int q = t & 3;
    const float4* xr = (const float4*)(x + (size_t)r * KDIM) + q * 4;
    const float4 v0 = xr[0], v1 = xr[1], v2 = xr[2], v3 = xr[3];
    float ss = v0.x * v0.x + v0.y * v0.y + v0.z * v0.z + v0.w * v0.w
             + v1.x * v1.x + v1.y * v1.y + v1.z * v1.z + v1.w * v1.w
             + v2.x * v2.x + v2.y * v2.y + v2.z * v2.z + v2.w * v2.w
             + v3.x * v3.x + v3.y * v3.y + v3.z * v3.z + v3.w * v3.w;
    ss += __shfl_xor(ss, 1, 64);
    ss += __shfl_xor(ss, 2, 64);
    // sqrt(2*log2(e)) = sqrt(2.88539008) = 1.69864404
    const float a = 1.69864404f * rsqrtf(fmaxf(ss, 1e-16f));
    const float vals[16] = {v0.x * a, v0.y * a, v0.z * a, v0.w * a,
                            v1.x * a, v1.y * a, v1.z * a, v1.w * a,
                            v2.x * a, v2.y * a, v2.z * a, v2.w * a,
                            v3.x * a, v3.y * a, v3.z * a, v3.w * a};
    union { unsigned short us[16]; uint4 v[2]; } o;
    #pragma unroll
    for (int k = 0; k < 16; k++) {
        __hip_bfloat16 b = __float2bfloat16(vals[k]);
        o.us[k] = *(unsigned short*)&b;
    }
    uint4* dst = (uint4*)(xnb + (size_t)r * KDIM);
    dst[q * 2] = o.v[0];
    dst[q * 2 + 1] = o.v[1];
    if (blockIdx.x == 0 && t == 0) { ctrl[0] = 0u; ctrl[1] = 0u; accum[0] = 0.0f; }
}

// ---- kernel B: symmetric tile-pair partial sums ---------------------------
// Block = upper-triangle tile pair (ti<=tj). 4 waves 2x2, 64x64/wave,
// mfma_f32_16x16x32_bf16 (A-frag: lane m=l&15 holds k=(l>>4)*8+e;
// C/D: col=l&15, row=(l>>4)*4+reg). Both tiles staged in LDS via
// global_load_lds width=16, XOR-swizzled chunk(r,q) at r*8 + (q^(r&7))
// (coalesced, 0 conflicts — r3-r11). Flat per-wave S stores. 32 KB LDS.
__global__ __launch_bounds__(256) void den_kernel(const unsigned short* __restrict__ xnb,
                                                  float* __restrict__ S,
                                                  float* __restrict__ num) {
    __shared__ float4 As[1024];  // 16 KB
    __shared__ float4 Bs[1024];  // 16 KB

    // triangular decode (f32; loops absorb rounding): blockIdx.x -> (ti, tj)
    const int bt = blockIdx.x;
    int ti = (int)((257.0f - sqrtf(66049.0f - 8.0f * (float)bt)) * 0.5f);
    while (ti * NTB - ti * (ti - 1) / 2 > bt) ti--;
    while ((ti + 1) * NTB - (ti + 1) * ti / 2 <= bt) ti++;
    const int tj = ti + (bt - (ti * NTB - ti * (ti - 1) / 2));
    const int ib = ti * NTILE, jb = tj * NTILE;
    const bool diag = (ti == tj);

    const int t = threadIdx.x;
    // staging: chunk c -> row r=c>>3, k-chunk q=(c&7)^(r&7). Global side is a
    // per-lane VGPR address (swizzle allowed); LDS side is uniform + lane*16.
    #pragma unroll
    for (int s = 0; s < 4; s++) {
        const int c = s * 256 + t;
        const int r = c >> 3;
        const int q = (c & 7) ^ (r & 7);
        load_lds16(xnb + (size_t)(ib + r) * KDIM + q * 8, &As[c]);
        load_lds16(xnb + (size_t)(jb + r) * KDIM + q * 8, &Bs[c]);
    }

    const int lane = t & 63, w = t >> 6;
    const int wi = w >> 1, wj = w & 1;
    const int m = lane & 15, p = lane >> 4;

    const f32x4 zero = {0.f, 0.f, 0.f, 0.f};
    f32x4 acc[4][4];
    #pragma unroll
    for (int it = 0; it < 4; it++)
        #pragma unroll
        for (int jt = 0; jt < 4; jt++) acc[it][jt] = zero;

    __syncthreads();   // compiler drains vmcnt before s_barrier (covers DMA)

    #pragma unroll
    for (int kc = 0; kc < 2; kc++) {
        short8 af[4], bf[4];
        const int qx = ((kc << 2) | p) ^ (m & 7);
        #pragma unroll
        for (int it = 0; it < 4; it++) {
            af[it] = *(const short8*)((const unsigned short*)As + ((wi * 64 + it * 16 + m) * 8 + qx) * 8);
            bf[it] = *(const short8*)((const unsigned short*)Bs + ((wj * 64 + it * 16 + m) * 8 + qx) * 8);
        }
        #pragma unroll
        for (int it = 0; it < 4; it++)
            #pragma unroll
            for (int jt = 0; jt < 4; jt++)
                acc[it][jt] = __builtin_amdgcn_mfma_f32_16x16x32_bf16(af[it], bf[jt], acc[it][jt], 0, 0, 0);
    }

    // epilogue: exp2; packed (v_pk_add_f32) accumulation of col/row partials
    f32x2 cs01 = {0.f, 0.f}, cs23 = {0.f, 0.f};
    float rs[16];
    #pragma unroll
    for (int it = 0; it < 4; it++) {
        #pragma unroll
        for (int reg = 0; reg < 4; reg++) {
            f32x2 e01, e23;
            e01.x = exp2_fast(acc[it][0][reg]);
            e01.y = exp2_fast(acc[it][1][reg]);
            e23.x = exp2_fast(acc[it][2][reg]);
            e23.y = exp2_fast(acc[it][3][reg]);
            cs01 += e01;
            cs23 += e23;
            const f32x2 rp = e01 + e23;
            rs[it * 4 + reg] = rp.x + rp.y;
        }
    }
    float cs[4] = {cs01.x, cs01.y, cs23.x, cs23.y};

    // colsum butterfly over p (value-halving): lane ends with column p*16+m
    {
        const bool hb = (p & 2) != 0;
        float s0 = hb ? cs[0] : cs[2], k0 = hb ? cs[2] : cs[0];
        float s1 = hb ? cs[1] : cs[3], k1 = hb ? cs[3] : cs[1];
        cs[0] = k0 + __shfl_xor(s0, 32, 64);
        cs[1] = k1 + __shfl_xor(s1, 32, 64);
        const bool lb = (p & 1) != 0;
        float s2 = lb ? cs[0] : cs[1], k2 = lb ? cs[1] : cs[0];
        cs[0] = k2 + __shfl_xor(s2, 16, 64);
    }
    // flat store: colsum partial (over wi-half rows) for column wj*64+p*16+m
    //   -> S[a=tj][b=2*ti+wi][c]   (contribution to den[jb + c])
    S[((size_t)tj * BSLOTS + 2 * ti + wi) * NTILE + wj * 64 + p * 16 + m] = cs[0];

    if (!diag) {
        // rowsum butterfly over m (value-halving, 15 shfl): lane ends with
        // row (m>>2)*16 + p*4 + (m&3) of its wi-half
        #pragma unroll
        for (int k = 0; k < 8; k++) {
            const float snd = (m & 8) ? rs[k] : rs[k + 8];
            const float kp  = (m & 8) ? rs[k + 8] : rs[k];
            rs[k] = kp + __shfl_xor(snd, 8, 64);
        }
        #pragma unroll
        for (int k = 0; k < 4; k++) {
            const float snd = (m & 4) ? rs[k] : rs[k + 4];
            const float kp  = (m & 4) ? rs[k + 4] : rs[k];
            rs[k] = kp + __shfl_xor(snd, 4, 64);
        }
        #pragma unroll
        for (int k = 0; k < 2; k++) {
            const float snd = (m & 2) ? rs[k] : rs[k + 2];
            const float kp  = (m & 2) ? rs[k + 2] : rs[k];
            rs[k] = kp + __shfl_xor(snd, 2, 64);
        }
        {
            const float snd = (m & 1) ? rs[0] : rs[1];
            const float kp  = (m & 1) ? rs[1] : rs[0];
            rs[0] = kp + __shfl_xor(snd, 1, 64);
        }
        // flat store: rowsum partial (over wj-half cols) for row
        // wi*64 + (m>>2)*16 + p*4 + (m&3)
        //   -> S[a=ti][b=2*tj+wj][r]   (contribution to den[ib + r]).
        // Diag blocks skip this; their b=2a slots are filled by colsums.
        S[((size_t)ti * BSLOTS + 2 * tj + wj) * NTILE + wi * 64 + ((m >> 2) * 16 + p * 4 + (m & 3))] = rs[0];
    } else if (wi == wj) {
        // num[j] = exp2(acc(row j^1, col j)) from the diagonal tile: element
        // (m^1, m) of sub-tile it lives in lane ((m^1)>>2, m), reg (m^1)&3.
        const int pc = m ^ 1;
        if ((pc >> 2) == p) {
            #pragma unroll
            for (int it = 0; it < 4; it++)
                num[jb + wj * 64 + it * 16 + m] = exp2_fast(acc[it][it][pc & 3]);
        }
    }
}

// ---- kernel C: den[a*128+c] = sum_b S[a][b][c]; ratio + global sum + log ---
// 128 blocks; ticket write of the final scalar (r6-verified).
__global__ __launch_bounds__(256) void reduce_kernel(const float* __restrict__ S,
                                                     const float* __restrict__ num,
                                                     unsigned int* __restrict__ ctrl,
                                                     float* __restrict__ accum,
                                                     float* __restrict__ out) {
    const int a = blockIdx.x;
    const int t = threadIdx.x;
    const int c = t & 127, h = t >> 7;     // h splits the 256 b-slots in two
    const float* base = S + (size_t)a * (BSLOTS * NTILE) + (size_t)h * 128 * NTILE + c;
    float s = 0.0f;
    #pragma unroll 8
    for (int b = 0; b < 128; b++) s += base[(size_t)b * NTILE];

    __shared__ float part[NTILE];
    __shared__ float wsum[4];
    if (h == 0) part[c] = s;
    __syncthreads();

    float r = 0.0f;
    if (h == 1) {
        const float E2 = 7.38905609893065f;  // exp(1/T)=exp(2): diagonal removal
        r = num[a * NTILE + c] / ((part[c] + s) - E2);
    }
    #pragma unroll
    for (int o = 32; o > 0; o >>= 1) r += __shfl_xor(r, o, 64);
    if ((t & 63) == 0) wsum[t >> 6] = r;
    __syncthreads();
    if (t == 0) {
        const float bsum = (wsum[0] + wsum[1]) + (wsum[2] + wsum[3]);
        __hip_atomic_fetch_add(accum, bsum, __ATOMIC_RELAXED, __HIP_MEMORY_SCOPE_AGENT);
        const unsigned int tk = __hip_atomic_fetch_add(&ctrl[1], 1u, __ATOMIC_ACQ_REL, __HIP_MEMORY_SCOPE_AGENT);
        if (tk == (unsigned)(NTB - 1)) {   // last block writes the loss
            const float total = __hip_atomic_load(accum, __ATOMIC_ACQUIRE, __HIP_MEMORY_SCOPE_AGENT);
            out[0] = -logf(total / (float)NROWS);
        }
    }
}

extern "C" void kernel_launch(void* const* d_in, const int* in_sizes, int n_in,
                              void* d_out, int out_size, void* d_ws, size_t ws_size,
                              hipStream_t stream) {
    const float* x = (const float*)d_in[0];
    float* out = (float*)d_out;

    // ws: xnb [2 MB bf16] | num [64 KB f32] | accum [1 f32] | ctrl [2 u32]
    //   | S [128 x 256 x 128 f32 = 16 MB]
    unsigned short* xnb = (unsigned short*)d_ws;
    float* num = (float*)((char*)d_ws + (size_t)NROWS * KDIM * sizeof(unsigned short));
    float* accum = num + NROWS;
    unsigned int* ctrl = (unsigned int*)(accum + 1);
    float* S = (float*)(ctrl + 2);

    normalize_kernel<<<NROWS / 64, 256, 0, stream>>>(x, xnb, ctrl, accum);
    den_kernel<<<NPAIRS, 256, 0, stream>>>(xnb, S, num);
    reduce_kernel<<<NTB, 256, 0, stream>>>(S, num, ctrl, accum, out);
}

// Round 13
// 100.416 us; speedup vs baseline: 1.8018x; 1.0609x over previous
//
#include <hip/hip_runtime.h>
#include <hip/hip_bf16.h>
#include <math.h>

// Contrastive (NT-Xent-like) loss over x[16384][64] fp32.
//   x_hat = sqrt(2*log2e) * x / ||x||   (so x_hat_i.x_hat_j = sim/T * log2e,
//                                        and exp(sim/T) = exp2(x_hat_i.x_hat_j))
//   den[j] = sum_i exp2(x_hat_i . x_hat_j) - e^2
//   num[j] = exp2(x_hat_{j^1} . x_hat_j)
//   out = -log( mean_j num[j] / den[j] )
//
// Round 13: REVERT to round 9 — the best-measured configuration (100.8 us).
// Full attribution from r9-r12:
//   r10 waves-clamp -> accumulator spill (VGPR 80->40, WRITE 345 MB): never
//     clamp when arch+acc regs exceed the cap (80+64=144 > 512/k).
//   r11 A-direct-from-global -> +16 us (8 L2 round-trips in the MFMA dep
//     chain; occupancy register-bound at 3 blocks/CU, so LDS savings moot).
//   r12 flat per-wave S stores -> den wash, but 2x S (16 MB) costs ~5 us in
//     WRITE + reduce traffic. LDS cross-wave combine + 8 MB S wins net.
// Envelope at this point: harness 0xAA poison-fill of 256 MB d_ws = ~44 us at
// 75-79% HBM peak (its own roofline, untouchable); den ~43 us at
// MfmaUtil+VALUBusy ~75% combined issue (structural plateau of this K=64
// tile shape); normalize ~4 us and reduce ~5 us at BW floors.
// Proven pieces: global_load_lds width=16 both tiles, XOR-swizzled
// conflict-free LDS (r3+), 2x2 wave MFMA 16x16x32_bf16, exp2 prescale,
// pk_add epilogue, value-halving butterflies (r6), bf16 prebake normalize
// (r8 lesson), kernel boundary as the only cross-XCD flush (r5/r7 lessons).

#define NROWS 16384
#define KDIM 64
#define NTILE 128
#define NTB (NROWS / NTILE)          // 128 tile-blocks per side
#define NPAIRS (NTB * (NTB + 1) / 2) // 8256 upper-triangle tile pairs

typedef __attribute__((ext_vector_type(8))) short short8;   // 8 bf16 = 4 VGPRs
typedef __attribute__((ext_vector_type(4))) float f32x4;
typedef __attribute__((ext_vector_type(2))) float f32x2;

__device__ __forceinline__ float exp2_fast(float x) {
#if __has_builtin(__builtin_amdgcn_exp2f)
    return __builtin_amdgcn_exp2f(x);   // bare v_exp_f32
#else
    return exp2f(x);
#endif
}

// async global->LDS DMA, 16 B per lane; LDS side must be uniform + lane*16.
__device__ __forceinline__ void load_lds16(const void* g, void* l) {
    __builtin_amdgcn_global_load_lds((const __attribute__((address_space(1))) unsigned int*)g,
                                     (__attribute__((address_space(3))) unsigned int*)l,
                                     16, 0, 0);
}

// ---- kernel A: row-normalize, prescale by sqrt(2*log2e) -> bf16 -----------
// 64 rows/block, 4 lanes/row, 16 floats/thread. Also zeroes ctrl/accum.
__global__ __launch_bounds__(256) void normalize_kernel(const float* __restrict__ x,
                                                        unsigned short* __restrict__ xnb,
                                                        unsigned int* __restrict__ ctrl,
                                                        float* __restrict__ accum) {
    const int t = threadIdx.x;
    const int r = blockIdx.x * 64 + (t >> 2);
    const int q = t & 3;
    const float4* xr = (const float4*)(x + (size_t)r * KDIM) + q * 4;
    const float4 v0 = xr[0], v1 = xr[1], v2 = xr[2], v3 = xr[3];
    float ss = v0.x * v0.x + v0.y * v0.y + v0.z * v0.z + v0.w * v0.w
             + v1.x * v1.x + v1.y * v1.y + v1.z * v1.z + v1.w * v1.w
             + v2.x * v2.x + v2.y * v2.y + v2.z * v2.z + v2.w * v2.w
             + v3.x * v3.x + v3.y * v3.y + v3.z * v3.z + v3.w * v3.w;
    ss += __shfl_xor(ss, 1, 64);
    ss += __shfl_xor(ss, 2, 64);
    // sqrt(2*log2(e)) = sqrt(2.88539008) = 1.69864404
    const float a = 1.69864404f * rsqrtf(fmaxf(ss, 1e-16f));
    const float vals[16] = {v0.x * a, v0.y * a, v0.z * a, v0.w * a,
                            v1.x * a, v1.y * a, v1.z * a, v1.w * a,
                            v2.x * a, v2.y * a, v2.z * a, v2.w * a,
                            v3.x * a, v3.y * a, v3.z * a, v3.w * a};
    union { unsigned short us[16]; uint4 v[2]; } o;
    #pragma unroll
    for (int k = 0; k < 16; k++) {
        __hip_bfloat16 b = __float2bfloat16(vals[k]);
        o.us[k] = *(unsigned short*)&b;
    }
    uint4* dst = (uint4*)(xnb + (size_t)r * KDIM);
    dst[q * 2] = o.v[0];
    dst[q * 2 + 1] = o.v[1];
    if (blockIdx.x == 0 && t == 0) { ctrl[0] = 0u; ctrl[1] = 0u; accum[0] = 0.0f; }
}

// ---- kernel B: symmetric tile-pair partial sums ---------------------------
// Block = upper-triangle tile pair (ti<=tj). 4 waves 2x2, 64x64/wave,
// mfma_f32_16x16x32_bf16 (A-frag: lane m=l&15 holds k=(l>>4)*8+e;
// C/D: col=l&15, row=(l>>4)*4+reg). Both tiles staged in LDS via
// global_load_lds width=16, XOR-swizzled chunk(r,q) at r*8 + (q^(r&7)):
// coalesced staging, 0 bank conflicts (verified r3-r12). 32 KB LDS.
__global__ __launch_bounds__(256) void den_kernel(const unsigned short* __restrict__ xnb,
                                                  float* __restrict__ S,
                                                  float* __restrict__ num) {
    __shared__ float4 As[1024];  // 16 KB; aliased as reduction scratch later
    __shared__ float4 Bs[1024];  // 16 KB

    // triangular decode (f32; loops absorb rounding): blockIdx.x -> (ti, tj)
    const int bt = blockIdx.x;
    int ti = (int)((257.0f - sqrtf(66049.0f - 8.0f * (float)bt)) * 0.5f);
    while (ti * NTB - ti * (ti - 1) / 2 > bt) ti--;
    while ((ti + 1) * NTB - (ti + 1) * ti / 2 <= bt) ti++;
    const int tj = ti + (bt - (ti * NTB - ti * (ti - 1) / 2));
    const int ib = ti * NTILE, jb = tj * NTILE;
    const bool diag = (ti == tj);

    const int t = threadIdx.x;
    // staging: chunk c -> row r=c>>3, k-chunk q=(c&7)^(r&7). Global side is a
    // per-lane VGPR address (swizzle allowed); LDS side is uniform + lane*16.
    #pragma unroll
    for (int s = 0; s < 4; s++) {
        const int c = s * 256 + t;
        const int r = c >> 3;
        const int q = (c & 7) ^ (r & 7);
        load_lds16(xnb + (size_t)(ib + r) * KDIM + q * 8, &As[c]);
        load_lds16(xnb + (size_t)(jb + r) * KDIM + q * 8, &Bs[c]);
    }
    __syncthreads();   // compiler drains vmcnt before s_barrier (covers DMA)

    const int lane = t & 63, w = t >> 6;
    const int wi = w >> 1, wj = w & 1;
    const int m = lane & 15, p = lane >> 4;

    const f32x4 zero = {0.f, 0.f, 0.f, 0.f};
    f32x4 acc[4][4];
    #pragma unroll
    for (int it = 0; it < 4; it++)
        #pragma unroll
        for (int jt = 0; jt < 4; jt++) acc[it][jt] = zero;

    #pragma unroll
    for (int kc = 0; kc < 2; kc++) {
        short8 af[4], bf[4];
        const int qx = ((kc << 2) | p) ^ (m & 7);
        #pragma unroll
        for (int it = 0; it < 4; it++) {
            af[it] = *(const short8*)((const unsigned short*)As + ((wi * 64 + it * 16 + m) * 8 + qx) * 8);
            bf[it] = *(const short8*)((const unsigned short*)Bs + ((wj * 64 + it * 16 + m) * 8 + qx) * 8);
        }
        #pragma unroll
        for (int it = 0; it < 4; it++)
            #pragma unroll
            for (int jt = 0; jt < 4; jt++)
                acc[it][jt] = __builtin_amdgcn_mfma_f32_16x16x32_bf16(af[it], bf[jt], acc[it][jt], 0, 0, 0);
    }

    // epilogue: exp2; packed (v_pk_add_f32) accumulation of col/row partials
    f32x2 cs01 = {0.f, 0.f}, cs23 = {0.f, 0.f};
    float rs[16];
    #pragma unroll
    for (int it = 0; it < 4; it++) {
        #pragma unroll
        for (int reg = 0; reg < 4; reg++) {
            f32x2 e01, e23;
            e01.x = exp2_fast(acc[it][0][reg]);
            e01.y = exp2_fast(acc[it][1][reg]);
            e23.x = exp2_fast(acc[it][2][reg]);
            e23.y = exp2_fast(acc[it][3][reg]);
            cs01 += e01;
            cs23 += e23;
            const f32x2 rp = e01 + e23;
            rs[it * 4 + reg] = rp.x + rp.y;
        }
    }
    float cs[4] = {cs01.x, cs01.y, cs23.x, cs23.y};

    // colsum butterfly over p (value-halving): lane ends with column p*16+m
    {
        const bool hb = (p & 2) != 0;
        float s0 = hb ? cs[0] : cs[2], k0 = hb ? cs[2] : cs[0];
        float s1 = hb ? cs[1] : cs[3], k1 = hb ? cs[3] : cs[1];
        cs[0] = k0 + __shfl_xor(s0, 32, 64);
        cs[1] = k1 + __shfl_xor(s1, 32, 64);
        const bool lb = (p & 1) != 0;
        float s2 = lb ? cs[0] : cs[1], k2 = lb ? cs[1] : cs[0];
        cs[0] = k2 + __shfl_xor(s2, 16, 64);
    }

    // rowsum butterfly over m (value-halving, 15 shfl): lane ends with row
    // (m>>2)*16 + p*4 + (m&3)
    if (!diag) {
        #pragma unroll
        for (int k = 0; k < 8; k++) {
            const float snd = (m & 8) ? rs[k] : rs[k + 8];
            const float kp  = (m & 8) ? rs[k + 8] : rs[k];
            rs[k] = kp + __shfl_xor(snd, 8, 64);
        }
        #pragma unroll
        for (int k = 0; k < 4; k++) {
            const float snd = (m & 4) ? rs[k] : rs[k + 4];
            const float kp  = (m & 4) ? rs[k + 4] : rs[k];
            rs[k] = kp + __shfl_xor(snd, 4, 64);
        }
        #pragma unroll
        for (int k = 0; k < 2; k++) {
            const float snd = (m & 2) ? rs[k] : rs[k + 2];
            const float kp  = (m & 2) ? rs[k + 2] : rs[k];
            rs[k] = kp + __shfl_xor(snd, 2, 64);
        }
        {
            const float snd = (m & 1) ? rs[0] : rs[1];
            const float kp  = (m & 1) ? rs[1] : rs[0];
            rs[0] = kp + __shfl_xor(snd, 1, 64);
        }
    } else if (wi == wj) {
        // num[j] = exp2(acc(row j^1, col j)) from the diagonal tile: element
        // (m^1, m) of sub-tile it lives in lane ((m^1)>>2, m), reg (m^1)&3.
        const int pc = m ^ 1;
        if ((pc >> 2) == p) {
            #pragma unroll
            for (int it = 0; it < 4; it++)
                num[jb + wj * 64 + it * 16 + m] = exp2_fast(acc[it][it][pc & 3]);
        }
    }

    // cross-wave combine through LDS (aliases dead As)
    float* red = (float*)As;   // [0..255] colsums by wi; [256..511] rowsums by wj
    __syncthreads();           // all waves done reading As/Bs
    red[wi * 128 + wj * 64 + p * 16 + m] = cs[0];
    if (!diag) red[256 + wj * 128 + wi * 64 + ((m >> 2) * 16 + p * 4 + (m & 3))] = rs[0];
    __syncthreads();

    // exactly-once coalesced partial stores (no atomics, no fences):
    //   colsums -> S[tj][ti][c] (den[jb+c]); rowsums -> S[ti][tj][r] (den[ib+r])
    if (t < NTILE) {
        S[((size_t)tj * NTB + ti) * NTILE + t] = red[t] + red[128 + t];
    } else if (!diag) {
        const int u = t - NTILE;
        S[((size_t)ti * NTB + tj) * NTILE + u] = red[256 + u] + red[256 + 128 + u];
    }
}

// ---- kernel C: den[a*128+c] = sum_b S[a][b][c]; ratio + global sum + log ---
// 128 blocks; ticket write of the final scalar (r6-verified).
__global__ __launch_bounds__(256) void reduce_kernel(const float* __restrict__ S,
                                                     const float* __restrict__ num,
                                                     unsigned int* __restrict__ ctrl,
                                                     float* __restrict__ accum,
                                                     float* __restrict__ out) {
    const int a = blockIdx.x;
    const int t = threadIdx.x;
    const int c = t & 127, h = t >> 7;     // h splits the b-range in two
    const float* base = S + (size_t)a * (NTB * NTILE) + (size_t)h * 64 * NTILE + c;
    float s = 0.0f;
    #pragma unroll 8
    for (int b = 0; b < 64; b++) s += base[(size_t)b * NTILE];

    __shared__ float part[NTILE];
    __shared__ float wsum[4];
    if (h == 0) part[c] = s;
    __syncthreads();

    float r = 0.0f;
    if (h == 1) {
        const float E2 = 7.38905609893065f;  // exp(1/T)=exp(2): diagonal removal
        r = num[a * NTILE + c] / ((part[c] + s) - E2);
    }
    #pragma unroll
    for (int o = 32; o > 0; o >>= 1) r += __shfl_xor(r, o, 64);
    if ((t & 63) == 0) wsum[t >> 6] = r;
    __syncthreads();
    if (t == 0) {
        const float bsum = (wsum[0] + wsum[1]) + (wsum[2] + wsum[3]);
        __hip_atomic_fetch_add(accum, bsum, __ATOMIC_RELAXED, __HIP_MEMORY_SCOPE_AGENT);
        const unsigned int tk = __hip_atomic_fetch_add(&ctrl[1], 1u, __ATOMIC_ACQ_REL, __HIP_MEMORY_SCOPE_AGENT);
        if (tk == (unsigned)(NTB - 1)) {   // last block writes the loss
            const float total = __hip_atomic_load(accum, __ATOMIC_ACQUIRE, __HIP_MEMORY_SCOPE_AGENT);
            out[0] = -logf(total / (float)NROWS);
        }
    }
}

extern "C" void kernel_launch(void* const* d_in, const int* in_sizes, int n_in,
                              void* d_out, int out_size, void* d_ws, size_t ws_size,
                              hipStream_t stream) {
    const float* x = (const float*)d_in[0];
    float* out = (float*)d_out;

    // ws: xnb [2 MB bf16] | num [64 KB f32] | accum [1 f32] | ctrl [2 u32] | S [8 MB f32]
    unsigned short* xnb = (unsigned short*)d_ws;
    float* num = (float*)((char*)d_ws + (size_t)NROWS * KDIM * sizeof(unsigned short));
    float* accum = num + NROWS;
    unsigned int* ctrl = (unsigned int*)(accum + 1);
    float* S = (float*)(ctrl + 2);

    normalize_kernel<<<NROWS / 64, 256, 0, stream>>>(x, xnb, ctrl, accum);
    den_kernel<<<NPAIRS, 256, 0, stream>>>(xnb, S, num);
    reduce_kernel<<<NTB, 256, 0, stream>>>(S, num, ctrl, accum, out);
}

// Round 14
// 99.897 us; speedup vs baseline: 1.8111x; 1.0052x over previous
//
#include <hip/hip_runtime.h>
#include <hip/hip_bf16.h>
#include <math.h>

// Contrastive (NT-Xent-like) loss over x[16384][64] fp32.
//   x_hat = sqrt(2*log2e) * x / ||x||   (so x_hat_i.x_hat_j = sim/T * log2e,
//                                        and exp(sim/T) = exp2(x_hat_i.x_hat_j))
//   den[j] = sum_i exp2(x_hat_i . x_hat_j) - e^2
//   num[j] = exp2(x_hat_{j^1} . x_hat_j)
//   out = -log( mean_j num[j] / den[j] )
//
// Round 14: r13 reproduced the r9 optimum (100.4 us; den 45.8). Ceiling
// arithmetic: den issue floor ~17 us at 100% VALU vs measured 46 at
// VALUBusy 57% — the gap is occupancy (144 unified regs -> 3 waves/SIMD,
// register-bound; LDS would allow 5 blocks/CU). One-line probe this round:
// __launch_bounds__(256, 4) caps the unified budget at 128 -> compiler must
// fit arch in 64 (acc=64). Unlike r10's cap of 85 (64 acc + 21 arch
// impossible -> acc spilled to scratch, 345 MB WRITE), 64 arch is feasible.
// Success signature: VGPR~64, occupancy ~35%, den ~37-40 us.
// Failure signature: WRITE_SIZE >> 50 MB, den > 80 us -> revert to r13.
// All else byte-identical to r13 (the 7-variant-verified optimum):
// global_load_lds width=16 both tiles, XOR-swizzled conflict-free LDS,
// 2x2 wave MFMA 16x16x32_bf16, exp2 prescale, pk_add epilogue,
// value-halving butterflies, LDS cross-wave combine + 8 MB S, bf16 prebake
// normalize, kernel boundary as the only cross-XCD flush.

#define NROWS 16384
#define KDIM 64
#define NTILE 128
#define NTB (NROWS / NTILE)          // 128 tile-blocks per side
#define NPAIRS (NTB * (NTB + 1) / 2) // 8256 upper-triangle tile pairs

typedef __attribute__((ext_vector_type(8))) short short8;   // 8 bf16 = 4 VGPRs
typedef __attribute__((ext_vector_type(4))) float f32x4;
typedef __attribute__((ext_vector_type(2))) float f32x2;

__device__ __forceinline__ float exp2_fast(float x) {
#if __has_builtin(__builtin_amdgcn_exp2f)
    return __builtin_amdgcn_exp2f(x);   // bare v_exp_f32
#else
    return exp2f(x);
#endif
}

// async global->LDS DMA, 16 B per lane; LDS side must be uniform + lane*16.
__device__ __forceinline__ void load_lds16(const void* g, void* l) {
    __builtin_amdgcn_global_load_lds((const __attribute__((address_space(1))) unsigned int*)g,
                                     (__attribute__((address_space(3))) unsigned int*)l,
                                     16, 0, 0);
}

// ---- kernel A: row-normalize, prescale by sqrt(2*log2e) -> bf16 -----------
// 64 rows/block, 4 lanes/row, 16 floats/thread. Also zeroes ctrl/accum.
__global__ __launch_bounds__(256) void normalize_kernel(const float* __restrict__ x,
                                                        unsigned short* __restrict__ xnb,
                                                        unsigned int* __restrict__ ctrl,
                                                        float* __restrict__ accum) {
    const int t = threadIdx.x;
    const int r = blockIdx.x * 64 + (t >> 2);
    const int q = t & 3;
    const float4* xr = (const float4*)(x + (size_t)r * KDIM) + q * 4;
    const float4 v0 = xr[0], v1 = xr[1], v2 = xr[2], v3 = xr[3];
    float ss = v0.x * v0.x + v0.y * v0.y + v0.z * v0.z + v0.w * v0.w
             + v1.x * v1.x + v1.y * v1.y + v1.z * v1.z + v1.w * v1.w
             + v2.x * v2.x + v2.y * v2.y + v2.z * v2.z + v2.w * v2.w
             + v3.x * v3.x + v3.y * v3.y + v3.z * v3.z + v3.w * v3.w;
    ss += __shfl_xor(ss, 1, 64);
    ss += __shfl_xor(ss, 2, 64);
    // sqrt(2*log2(e)) = sqrt(2.88539008) = 1.69864404
    const float a = 1.69864404f * rsqrtf(fmaxf(ss, 1e-16f));
    const float vals[16] = {v0.x * a, v0.y * a, v0.z * a, v0.w * a,
                            v1.x * a, v1.y * a, v1.z * a, v1.w * a,
                            v2.x * a, v2.y * a, v2.z * a, v2.w * a,
                            v3.x * a, v3.y * a, v3.z * a, v3.w * a};
    union { unsigned short us[16]; uint4 v[2]; } o;
    #pragma unroll
    for (int k = 0; k < 16; k++) {
        __hip_bfloat16 b = __float2bfloat16(vals[k]);
        o.us[k] = *(unsigned short*)&b;
    }
    uint4* dst = (uint4*)(xnb + (size_t)r * KDIM);
    dst[q * 2] = o.v[0];
    dst[q * 2 + 1] = o.v[1];
    if (blockIdx.x == 0 && t == 0) { ctrl[0] = 0u; ctrl[1] = 0u; accum[0] = 0.0f; }
}

// ---- kernel B: symmetric tile-pair partial sums ---------------------------
// Block = upper-triangle tile pair (ti<=tj). 4 waves 2x2, 64x64/wave,
// mfma_f32_16x16x32_bf16 (A-frag: lane m=l&15 holds k=(l>>4)*8+e;
// C/D: col=l&15, row=(l>>4)*4+reg). Both tiles staged in LDS via
// global_load_lds width=16, XOR-swizzled chunk(r,q) at r*8 + (q^(r&7)):
// coalesced staging, 0 bank conflicts (verified r3-r13). 32 KB LDS.
// launch_bounds(256,4): cap 128 unified regs -> 4 waves/SIMD (see header).
__global__ __launch_bounds__(256, 4) void den_kernel(const unsigned short* __restrict__ xnb,
                                                     float* __restrict__ S,
                                                     float* __restrict__ num) {
    __shared__ float4 As[1024];  // 16 KB; aliased as reduction scratch later
    __shared__ float4 Bs[1024];  // 16 KB

    // triangular decode (f32; loops absorb rounding): blockIdx.x -> (ti, tj)
    const int bt = blockIdx.x;
    int ti = (int)((257.0f - sqrtf(66049.0f - 8.0f * (float)bt)) * 0.5f);
    while (ti * NTB - ti * (ti - 1) / 2 > bt) ti--;
    while ((ti + 1) * NTB - (ti + 1) * ti / 2 <= bt) ti++;
    const int tj = ti + (bt - (ti * NTB - ti * (ti - 1) / 2));
    const int ib = ti * NTILE, jb = tj * NTILE;
    const bool diag = (ti == tj);

    const int t = threadIdx.x;
    // staging: chunk c -> row r=c>>3, k-chunk q=(c&7)^(r&7). Global side is a
    // per-lane VGPR address (swizzle allowed); LDS side is uniform + lane*16.
    #pragma unroll
    for (int s = 0; s < 4; s++) {
        const int c = s * 256 + t;
        const int r = c >> 3;
        const int q = (c & 7) ^ (r & 7);
        load_lds16(xnb + (size_t)(ib + r) * KDIM + q * 8, &As[c]);
        load_lds16(xnb + (size_t)(jb + r) * KDIM + q * 8, &Bs[c]);
    }
    __syncthreads();   // compiler drains vmcnt before s_barrier (covers DMA)

    const int lane = t & 63, w = t >> 6;
    const int wi = w >> 1, wj = w & 1;
    const int m = lane & 15, p = lane >> 4;

    const f32x4 zero = {0.f, 0.f, 0.f, 0.f};
    f32x4 acc[4][4];
    #pragma unroll
    for (int it = 0; it < 4; it++)
        #pragma unroll
        for (int jt = 0; jt < 4; jt++) acc[it][jt] = zero;

    #pragma unroll
    for (int kc = 0; kc < 2; kc++) {
        short8 af[4], bf[4];
        const int qx = ((kc << 2) | p) ^ (m & 7);
        #pragma unroll
        for (int it = 0; it < 4; it++) {
            af[it] = *(const short8*)((const unsigned short*)As + ((wi * 64 + it * 16 + m) * 8 + qx) * 8);
            bf[it] = *(const short8*)((const unsigned short*)Bs + ((wj * 64 + it * 16 + m) * 8 + qx) * 8);
        }
        #pragma unroll
        for (int it = 0; it < 4; it++)
            #pragma unroll
            for (int jt = 0; jt < 4; jt++)
                acc[it][jt] = __builtin_amdgcn_mfma_f32_16x16x32_bf16(af[it], bf[jt], acc[it][jt], 0, 0, 0);
    }

    // epilogue: exp2; packed (v_pk_add_f32) accumulation of col/row partials
    f32x2 cs01 = {0.f, 0.f}, cs23 = {0.f, 0.f};
    float rs[16];
    #pragma unroll
    for (int it = 0; it < 4; it++) {
        #pragma unroll
        for (int reg = 0; reg < 4; reg++) {
            f32x2 e01, e23;
            e01.x = exp2_fast(acc[it][0][reg]);
            e01.y = exp2_fast(acc[it][1][reg]);
            e23.x = exp2_fast(acc[it][2][reg]);
            e23.y = exp2_fast(acc[it][3][reg]);
            cs01 += e01;
            cs23 += e23;
            const f32x2 rp = e01 + e23;
            rs[it * 4 + reg] = rp.x + rp.y;
        }
    }
    float cs[4] = {cs01.x, cs01.y, cs23.x, cs23.y};

    // colsum butterfly over p (value-halving): lane ends with column p*16+m
    {
        const bool hb = (p & 2) != 0;
        float s0 = hb ? cs[0] : cs[2], k0 = hb ? cs[2] : cs[0];
        float s1 = hb ? cs[1] : cs[3], k1 = hb ? cs[3] : cs[1];
        cs[0] = k0 + __shfl_xor(s0, 32, 64);
        cs[1] = k1 + __shfl_xor(s1, 32, 64);
        const bool lb = (p & 1) != 0;
        float s2 = lb ? cs[0] : cs[1], k2 = lb ? cs[1] : cs[0];
        cs[0] = k2 + __shfl_xor(s2, 16, 64);
    }

    // rowsum butterfly over m (value-halving, 15 shfl): lane ends with row
    // (m>>2)*16 + p*4 + (m&3)
    if (!diag) {
        #pragma unroll
        for (int k = 0; k < 8; k++) {
            const float snd = (m & 8) ? rs[k] : rs[k + 8];
            const float kp  = (m & 8) ? rs[k + 8] : rs[k];
            rs[k] = kp + __shfl_xor(snd, 8, 64);
        }
        #pragma unroll
        for (int k = 0; k < 4; k++) {
            const float snd = (m & 4) ? rs[k] : rs[k + 4];
            const float kp  = (m & 4) ? rs[k + 4] : rs[k];
            rs[k] = kp + __shfl_xor(snd, 4, 64);
        }
        #pragma unroll
        for (int k = 0; k < 2; k++) {
            const float snd = (m & 2) ? rs[k] : rs[k + 2];
            const float kp  = (m & 2) ? rs[k + 2] : rs[k];
            rs[k] = kp + __shfl_xor(snd, 2, 64);
        }
        {
            const float snd = (m & 1) ? rs[0] : rs[1];
            const float kp  = (m & 1) ? rs[1] : rs[0];
            rs[0] = kp + __shfl_xor(snd, 1, 64);
        }
    } else if (wi == wj) {
        // num[j] = exp2(acc(row j^1, col j)) from the diagonal tile: element
        // (m^1, m) of sub-tile it lives in lane ((m^1)>>2, m), reg (m^1)&3.
        const int pc = m ^ 1;
        if ((pc >> 2) == p) {
            #pragma unroll
            for (int it = 0; it < 4; it++)
                num[jb + wj * 64 + it * 16 + m] = exp2_fast(acc[it][it][pc & 3]);
        }
    }

    // cross-wave combine through LDS (aliases dead As)
    float* red = (float*)As;   // [0..255] colsums by wi; [256..511] rowsums by wj
    __syncthreads();           // all waves done reading As/Bs
    red[wi * 128 + wj * 64 + p * 16 + m] = cs[0];
    if (!diag) red[256 + wj * 128 + wi * 64 + ((m >> 2) * 16 + p * 4 + (m & 3))] = rs[0];
    __syncthreads();

    // exactly-once coalesced partial stores (no atomics, no fences):
    //   colsums -> S[tj][ti][c] (den[jb+c]); rowsums -> S[ti][tj][r] (den[ib+r])
    if (t < NTILE) {
        S[((size_t)tj * NTB + ti) * NTILE + t] = red[t] + red[128 + t];
    } else if (!diag) {
        const int u = t - NTILE;
        S[((size_t)ti * NTB + tj) * NTILE + u] = red[256 + u] + red[256 + 128 + u];
    }
}

// ---- kernel C: den[a*128+c] = sum_b S[a][b][c]; ratio + global sum + log ---
// 128 blocks; ticket write of the final scalar (r6-verified).
__global__ __launch_bounds__(256) void reduce_kernel(const float* __restrict__ S,
                                                     const float* __restrict__ num,
                                                     unsigned int* __restrict__ ctrl,
                                                     float* __restrict__ accum,
                                                     float* __restrict__ out) {
    const int a = blockIdx.x;
    const int t = threadIdx.x;
    const int c = t & 127, h = t >> 7;     // h splits the b-range in two
    const float* base = S + (size_t)a * (NTB * NTILE) + (size_t)h * 64 * NTILE + c;
    float s = 0.0f;
    #pragma unroll 8
    for (int b = 0; b < 64; b++) s += base[(size_t)b * NTILE];

    __shared__ float part[NTILE];
    __shared__ float wsum[4];
    if (h == 0) part[c] = s;
    __syncthreads();

    float r = 0.0f;
    if (h == 1) {
        const float E2 = 7.38905609893065f;  // exp(1/T)=exp(2): diagonal removal
        r = num[a * NTILE + c] / ((part[c] + s) - E2);
    }
    #pragma unroll
    for (int o = 32; o > 0; o >>= 1) r += __shfl_xor(r, o, 64);
    if ((t & 63) == 0) wsum[t >> 6] = r;
    __syncthreads();
    if (t == 0) {
        const float bsum = (wsum[0] + wsum[1]) + (wsum[2] + wsum[3]);
        __hip_atomic_fetch_add(accum, bsum, __ATOMIC_RELAXED, __HIP_MEMORY_SCOPE_AGENT);
        const unsigned int tk = __hip_atomic_fetch_add(&ctrl[1], 1u, __ATOMIC_ACQ_REL, __HIP_MEMORY_SCOPE_AGENT);
        if (tk == (unsigned)(NTB - 1)) {   // last block writes the loss
            const float total = __hip_atomic_load(accum, __ATOMIC_ACQUIRE, __HIP_MEMORY_SCOPE_AGENT);
            out[0] = -logf(total / (float)NROWS);
        }
    }
}

extern "C" void kernel_launch(void* const* d_in, const int* in_sizes, int n_in,
                              void* d_out, int out_size, void* d_ws, size_t ws_size,
                              hipStream_t stream) {
    const float* x = (const float*)d_in[0];
    float* out = (float*)d_out;

    // ws: xnb [2 MB bf16] | num [64 KB f32] | accum [1 f32] | ctrl [2 u32] | S [8 MB f32]
    unsigned short* xnb = (unsigned short*)d_ws;
    float* num = (float*)((char*)d_ws + (size_t)NROWS * KDIM * sizeof(unsigned short));
    float* accum = num + NROWS;
    unsigned int* ctrl = (unsigned int*)(accum + 1);
    float* S = (float*)(ctrl + 2);

    normalize_kernel<<<NROWS / 64, 256, 0, stream>>>(x, xnb, ctrl, accum);
    den_kernel<<<NPAIRS, 256, 0, stream>>>(xnb, S, num);
    reduce_kernel<<<NTB, 256, 0, stream>>>(S, num, ctrl, accum, out);
}